// Round 10
// baseline (759.921 us; speedup 1.0000x reference)
//
#include <hip/hip_runtime.h>
#include <hip/hip_bf16.h>

typedef __bf16 bf16_t;
typedef bf16_t bf16x8 __attribute__((ext_vector_type(8)));
typedef float f32x4 __attribute__((ext_vector_type(4)));

#define MFMA16(a, b, c) __builtin_amdgcn_mfma_f32_16x16x32_bf16(a, b, c, 0, 0, 0)
#define NEGV -1e30f

__device__ __forceinline__ unsigned short f2bf(float f) {
  union { float f; unsigned int u; } v; v.f = f;
  unsigned int r = v.u + 0x7FFFu + ((v.u >> 16) & 1u);
  return (unsigned short)(r >> 16);
}

__device__ __forceinline__ void gload16(const unsigned short* g, unsigned short* l) {
  __builtin_amdgcn_global_load_lds(
      (const __attribute__((address_space(1))) void*)g,
      (__attribute__((address_space(3))) void*)l, 16, 0, 0);
}

// ============ Kernel P1: x [B,D,L] fp32 -> xT [B,L,D] bf16 ============
__global__ __launch_bounds__(256) void x_transpose(
    const float* __restrict__ x, unsigned short* __restrict__ xT)
{
  const int b = blockIdx.z;
  const int l0 = blockIdx.x * 64, d0 = blockIdx.y * 64;
  __shared__ __align__(16) unsigned short T[64][68];
  const int tid = threadIdx.x;
  const int dl = tid >> 4, lc = (tid & 15) * 4;
#pragma unroll
  for (int rep = 0; rep < 4; ++rep) {
    int d = dl + rep * 16;
    float4 v = *reinterpret_cast<const float4*>(
        x + ((size_t)b * 1024 + d0 + d) * 1024 + l0 + lc);
    ushort4 u;
    u.x = f2bf(v.x); u.y = f2bf(v.y); u.z = f2bf(v.z); u.w = f2bf(v.w);
    *reinterpret_cast<ushort4*>(&T[d][lc]) = u;
  }
  __syncthreads();
  const int dbase = (tid & 15) * 4, lbase = (tid >> 4) * 4;
  ushort4 r0 = *reinterpret_cast<const ushort4*>(&T[dbase + 0][lbase]);
  ushort4 r1 = *reinterpret_cast<const ushort4*>(&T[dbase + 1][lbase]);
  ushort4 r2 = *reinterpret_cast<const ushort4*>(&T[dbase + 2][lbase]);
  ushort4 r3 = *reinterpret_cast<const ushort4*>(&T[dbase + 3][lbase]);
  ushort4 w0 = {r0.x, r1.x, r2.x, r3.x};
  ushort4 w1 = {r0.y, r1.y, r2.y, r3.y};
  ushort4 w2 = {r0.z, r1.z, r2.z, r3.z};
  ushort4 w3 = {r0.w, r1.w, r2.w, r3.w};
  unsigned short* op = xT + ((size_t)b * 1024 + l0 + lbase) * 1024 + d0 + dbase;
  *reinterpret_cast<ushort4*>(op) = w0;
  *reinterpret_cast<ushort4*>(op + 1024) = w1;
  *reinterpret_cast<ushort4*>(op + 2048) = w2;
  *reinterpret_cast<ushort4*>(op + 3072) = w3;
}

// ============ Kernel P2: weights fp32 -> bf16 (Wqkv concat + Wo) ============
__global__ __launch_bounds__(256) void w_convert(
    const float* __restrict__ wq, const float* __restrict__ wk,
    const float* __restrict__ wv, const float* __restrict__ wo,
    unsigned short* __restrict__ Wqkv, unsigned short* __restrict__ Wo)
{
  const int z = blockIdx.y;
  const float* src = (z == 0) ? wq : (z == 1) ? wk : (z == 2) ? wv : wo;
  unsigned short* dst = (z < 3) ? Wqkv + (size_t)z * 1048576 : Wo;
  size_t off = ((size_t)blockIdx.x * 256 + threadIdx.x) * 4;
  float4 v = *reinterpret_cast<const float4*>(src + off);
  ushort4 u = {f2bf(v.x), f2bf(v.y), f2bf(v.z), f2bf(v.w)};
  *reinterpret_cast<ushort4*>(dst + off) = u;
}

// ============ Kernel A: fused QKV GEMM — 256^2 / BK64, 8-phase counted-vmcnt ==
__global__ __launch_bounds__(512, 2) void qkv_gemm8(
    const unsigned short* __restrict__ xT, const unsigned short* __restrict__ Wqkv,
    const float* __restrict__ bq, const float* __restrict__ bk, const float* __restrict__ bv,
    unsigned short* __restrict__ Q, unsigned short* __restrict__ K,
    unsigned short* __restrict__ Vt)
{
  __shared__ __align__(16) unsigned short lds[2][4][8192];  // 128 KiB

  const int tid = threadIdx.x;
  const int wave = tid >> 6, lane = tid & 63;
  const int lr = lane & 15, lg = lane >> 4;
  const int wr = wave >> 2, wc = wave & 3;

  const int bid = blockIdx.x;
  const int swz = (bid & 7) * 192 + (bid >> 3);  // 1536 % 8 == 0: bijective
  const int mt = swz / 12, nt = swz % 12;
  const int m0 = mt * 256, n0 = nt * 256;

  const unsigned short* Ag = xT + (size_t)m0 * 1024;
  const unsigned short* Bg = Wqkv + (size_t)n0 * 1024;

  const int srow = tid >> 2;
  const int schk = (tid & 3) * 8;

#define STAGE_HT(BUF, REG, TI)                                                 \
  {                                                                            \
    const int kt_ = ((TI) < 16 ? (TI) : 15) * 64 + (((REG)&1) * 32) + schk;    \
    const unsigned short* gp_ = (((REG) < 2) ? Ag : Bg);                       \
    _Pragma("unroll")                                                          \
    for (int j_ = 0; j_ < 2; ++j_)                                             \
      gload16(gp_ + (size_t)(j_ * 128 + srow) * 1024 + kt_,                    \
              &lds[BUF][REG][j_ * 4096 + tid * 8]);                            \
  }

#define LDA(BUF, KK, MH, AR)                                                   \
  _Pragma("unroll")                                                            \
  for (int mi_ = 0; mi_ < 4; ++mi_)                                            \
    AR[mi_] = *reinterpret_cast<const bf16x8*>(                                \
        &lds[BUF][KK][(wr * 128 + (MH)*64 + mi_ * 16 + lr) * 32 + lg * 8]);

#define LDB(BUF, KK, BR)                                                       \
  _Pragma("unroll")                                                            \
  for (int n_ = 0; n_ < 4; ++n_)                                               \
    BR[n_] = *reinterpret_cast<const bf16x8*>(                                 \
        &lds[BUF][2 + (KK)][(wc * 64 + n_ * 16 + lr) * 32 + lg * 8]);

#define MM(AR, BR, MH)                                                         \
  __builtin_amdgcn_s_setprio(1);                                               \
  _Pragma("unroll")                                                            \
  for (int mi_ = 0; mi_ < 4; ++mi_)                                            \
    _Pragma("unroll")                                                          \
    for (int n_ = 0; n_ < 4; ++n_)                                             \
      acc[(MH)*4 + mi_][n_] = MFMA16(AR[mi_], BR[n_], acc[(MH)*4 + mi_][n_]);  \
  __builtin_amdgcn_s_setprio(0);

#define BAR()                                                                  \
  {                                                                            \
    asm volatile("" ::: "memory");                                             \
    __builtin_amdgcn_s_barrier();                                              \
    asm volatile("" ::: "memory");                                             \
  }
#define VMW() asm volatile("s_waitcnt vmcnt(10)" ::: "memory")

  f32x4 acc[8][4];
#pragma unroll
  for (int m = 0; m < 8; ++m)
#pragma unroll
    for (int n = 0; n < 4; ++n) acc[m][n] = (f32x4){0.f, 0.f, 0.f, 0.f};

  STAGE_HT(0, 2, 0); STAGE_HT(0, 0, 0); STAGE_HT(0, 3, 0); STAGE_HT(0, 1, 0);
  STAGE_HT(1, 2, 1); STAGE_HT(1, 0, 1); STAGE_HT(1, 3, 1);
  VMW();
  BAR();

  for (int it = 0; it < 8; ++it) {
    const int T = 2 * it;
    bf16x8 a0[4], a1[4], b0[4], b1[4];
    LDB(0, 0, b0); LDA(0, 0, 0, a0);
    STAGE_HT(1, 1, T + 1);
    BAR();
    MM(a0, b0, 0);
    BAR();
    LDA(0, 0, 1, a1);
    STAGE_HT(0, 2, T + 2);
    BAR();
    MM(a1, b0, 1);
    VMW(); BAR();
    LDB(0, 1, b1); LDA(0, 1, 0, a0);
    STAGE_HT(0, 0, T + 2);
    BAR();
    MM(a0, b1, 0);
    BAR();
    LDA(0, 1, 1, a1);
    STAGE_HT(0, 3, T + 2);
    BAR();
    MM(a1, b1, 1);
    VMW(); BAR();
    LDB(1, 0, b0); LDA(1, 0, 0, a0);
    STAGE_HT(0, 1, T + 2);
    BAR();
    MM(a0, b0, 0);
    BAR();
    LDA(1, 0, 1, a1);
    STAGE_HT(1, 2, T + 3);
    BAR();
    MM(a1, b0, 1);
    VMW(); BAR();
    LDB(1, 1, b1); LDA(1, 1, 0, a0);
    STAGE_HT(1, 0, T + 3);
    BAR();
    MM(a0, b1, 0);
    BAR();
    LDA(1, 1, 1, a1);
    STAGE_HT(1, 3, T + 3);
    BAR();
    MM(a1, b1, 1);
    VMW(); BAR();
  }

  const int zi = n0 >> 10;
  const float* bias = (zi == 0) ? bq : (zi == 1) ? bk : bv;
  const int b = m0 >> 10;
  const int lbase = (m0 & 1023) + wr * 128;

  if (zi < 2) {
    unsigned short* op = ((zi == 0) ? Q : K);
#pragma unroll
    for (int n = 0; n < 4; ++n) {
      const int col = (n0 & 1023) + wc * 64 + n * 16 + lr;
      const int h = col >> 7, d = col & 127;
      const float bs = bias[col];
      unsigned short* hp = op + ((size_t)b * 8 + h) * 131072 + d;
#pragma unroll
      for (int m = 0; m < 8; ++m)
#pragma unroll
        for (int ii = 0; ii < 4; ++ii) {
          int l = lbase + m * 16 + lg * 4 + ii;
          hp[(size_t)l * 128] = f2bf(acc[m][n][ii] + bs);
        }
    }
  } else {
#pragma unroll
    for (int n = 0; n < 4; ++n) {
      const int col = (n0 & 1023) + wc * 64 + n * 16 + lr;
      const int h = col >> 7, d = col & 127;
      const float bs = bias[col];
      unsigned short* hp = Vt + ((size_t)b * 8 + h) * 131072 + (size_t)d * 1024;
#pragma unroll
      for (int m = 0; m < 8; ++m) {
        int l = lbase + m * 16 + lg * 4;
        ushort4 u = {f2bf(acc[m][n][0] + bs), f2bf(acc[m][n][1] + bs),
                     f2bf(acc[m][n][2] + bs), f2bf(acc[m][n][3] + bs)};
        *reinterpret_cast<ushort4*>(&hp[l]) = u;
      }
    }
  }
#undef STAGE_HT
}

// ============ Kernel C: out projection — 256^2 / BK64, 8-phase ============
__global__ __launch_bounds__(512, 2) void out_gemm8(
    const unsigned short* __restrict__ Wo, const unsigned short* __restrict__ O,
    const float* __restrict__ bo, float* __restrict__ out)
{
  __shared__ __align__(16) unsigned short lds[2][4][8192];

  const int tid = threadIdx.x;
  const int wave = tid >> 6, lane = tid & 63;
  const int lr = lane & 15, lg = lane >> 4;
  const int wr = wave >> 2, wc = wave & 3;

  const int b = blockIdx.y;
  const int bid = blockIdx.x;                  // 16 tiles per batch
  const int swz = (bid & 7) * 2 + (bid >> 3);  // bijective (16 % 8 == 0)
  const int mt = swz >> 2, nt = swz & 3;
  const int d0 = mt * 256, l0 = nt * 256;

  const unsigned short* Ag = Wo + (size_t)d0 * 1024;
  const unsigned short* Og = O + (size_t)b * 8 * 131072;

  const int srow = tid >> 2;
  const int schk = (tid & 3) * 8;

#define STAGE_HT(BUF, REG, TI)                                                 \
  {                                                                            \
    const int kt_ = ((TI) < 16 ? (TI) : 15) * 64 + (((REG)&1) * 32) + schk;    \
    if ((REG) < 2) {                                                           \
      _Pragma("unroll")                                                        \
      for (int j_ = 0; j_ < 2; ++j_)                                           \
        gload16(Ag + (size_t)(j_ * 128 + srow) * 1024 + kt_,                   \
                &lds[BUF][REG][j_ * 4096 + tid * 8]);                          \
    } else {                                                                   \
      const int h_ = kt_ >> 7, dk_ = kt_ & 127;                                \
      _Pragma("unroll")                                                        \
      for (int j_ = 0; j_ < 2; ++j_)                                           \
        gload16(Og + (size_t)h_ * 131072 +                                     \
                    (size_t)(l0 + j_ * 128 + srow) * 128 + dk_,                \
                &lds[BUF][REG][j_ * 4096 + tid * 8]);                          \
    }                                                                          \
  }

  f32x4 acc[8][4];
#pragma unroll
  for (int m = 0; m < 8; ++m)
#pragma unroll
    for (int n = 0; n < 4; ++n) acc[m][n] = (f32x4){0.f, 0.f, 0.f, 0.f};

  STAGE_HT(0, 2, 0); STAGE_HT(0, 0, 0); STAGE_HT(0, 3, 0); STAGE_HT(0, 1, 0);
  STAGE_HT(1, 2, 1); STAGE_HT(1, 0, 1); STAGE_HT(1, 3, 1);
  VMW();
  BAR();

  for (int it = 0; it < 8; ++it) {
    const int T = 2 * it;
    bf16x8 a0[4], a1[4], b0[4], b1[4];
    LDB(0, 0, b0); LDA(0, 0, 0, a0);
    STAGE_HT(1, 1, T + 1);
    BAR();
    MM(a0, b0, 0);
    BAR();
    LDA(0, 0, 1, a1);
    STAGE_HT(0, 2, T + 2);
    BAR();
    MM(a1, b0, 1);
    VMW(); BAR();
    LDB(0, 1, b1); LDA(0, 1, 0, a0);
    STAGE_HT(0, 0, T + 2);
    BAR();
    MM(a0, b1, 0);
    BAR();
    LDA(0, 1, 1, a1);
    STAGE_HT(0, 3, T + 2);
    BAR();
    MM(a1, b1, 1);
    VMW(); BAR();
    LDB(1, 0, b0); LDA(1, 0, 0, a0);
    STAGE_HT(0, 1, T + 2);
    BAR();
    MM(a0, b0, 0);
    BAR();
    LDA(1, 0, 1, a1);
    STAGE_HT(1, 2, T + 3);
    BAR();
    MM(a1, b0, 1);
    VMW(); BAR();
    LDB(1, 1, b1); LDA(1, 1, 0, a0);
    STAGE_HT(1, 0, T + 3);
    BAR();
    MM(a0, b1, 0);
    BAR();
    LDA(1, 1, 1, a1);
    STAGE_HT(1, 3, T + 3);
    BAR();
    MM(a1, b1, 1);
    VMW(); BAR();
  }

#pragma unroll
  for (int m = 0; m < 8; ++m) {
#pragma unroll
    for (int ii = 0; ii < 4; ++ii) {
      int dr = d0 + wr * 128 + m * 16 + lg * 4 + ii;
      float bs = bo[dr];
      float* orow = out + ((size_t)b * 1024 + dr) * 1024 + l0 + wc * 64 + lr;
#pragma unroll
      for (int n = 0; n < 4; ++n)
        orow[n * 16] = acc[m][n][ii] + bs;
    }
  }
#undef STAGE_HT
#undef LDA
#undef LDB
#undef MM
#undef BAR
#undef VMW
}

// ============ Kernel B: flash attention — QBLK=32/wave, KVBLK=64 ============
// Single-buffered K/V (45.5 KiB -> 3 blocks/CU). K staged under softmax+PV
// (Kl dead after QK); V staged at tile end (short exposed L2-hit latency,
// covered by 3 resident blocks). XCD-aware 1D grid keeps K/V per-XCD L2-hot.
__global__ __launch_bounds__(256, 3) void flash_attn(
    const unsigned short* __restrict__ Q, const unsigned short* __restrict__ Kb,
    const unsigned short* __restrict__ Vt, const int* __restrict__ mask,
    unsigned short* __restrict__ O)
{
  const int tid = threadIdx.x, wave = tid >> 6, lane = tid & 63;
  const int lr = lane & 15, lg = lane >> 4;
  const int id = blockIdx.x;
  const int qt = (id >> 3) & 7;
  const int bh_ = ((id >> 6) << 3) | (id & 7);
  const int b = bh_ >> 3;
  const size_t bh = (size_t)bh_;
  const unsigned short* Qp = Q + bh * 131072;
  const unsigned short* Kp = Kb + bh * 131072;
  const unsigned short* Vp = Vt + bh * 131072;
  unsigned short* Op = O + bh * 131072;
  const int q0 = qt * 128 + wave * 32;
  const float SC2 = 0.12751744f;        // (1/sqrt(128)) * log2(e)
  const float NEG2 = -1.442695e30f;     // -1e30 * log2(e)

  __shared__ __align__(16) unsigned short Kl[64 * 128];      // 16 KiB
  __shared__ __align__(16) unsigned short Vl[128 * 64];      // 16 KiB
  __shared__ __align__(16) unsigned short plds[4][16 * 76];  // 9.5 KiB
  __shared__ float pen[1024];                                // 4 KiB

  {
    const int4 mv = *reinterpret_cast<const int4*>(mask + b * 1024 + tid * 4);
    float4 pv;
    pv.x = mv.x ? NEG2 : 0.f; pv.y = mv.y ? NEG2 : 0.f;
    pv.z = mv.z ? NEG2 : 0.f; pv.w = mv.w ? NEG2 : 0.f;
    *reinterpret_cast<float4*>(&pen[tid * 4]) = pv;
  }

  unsigned short* myP = plds[wave];

  bf16x8 aq0[4], aq1[4];
#pragma unroll
  for (int c = 0; c < 4; ++c) {
    aq0[c] = *reinterpret_cast<const bf16x8*>(
        &Qp[(size_t)(q0 + lr) * 128 + c * 32 + lg * 8]);
    aq1[c] = *reinterpret_cast<const bf16x8*>(
        &Qp[(size_t)(q0 + 16 + lr) * 128 + c * 32 + lg * 8]);
  }

  // K: [64][128] rows 256B, byte ^= (row&7)<<4. V: [128][64] rows 128B, same XOR.
#define STAGE_K(ktv)                                                            \
  {                                                                             \
    _Pragma("unroll")                                                           \
    for (int i = 0; i < 4; ++i) {                                               \
      int krow = i * 16 + (tid >> 4);                                           \
      int kcb = ((tid & 15) * 16) ^ ((krow & 7) << 4);                          \
      gload16(Kp + (size_t)((ktv) + krow) * 128 + (kcb >> 1),                   \
              &Kl[i * 2048 + tid * 8]);                                         \
    }                                                                           \
  }
#define STAGE_V(ktv)                                                            \
  {                                                                             \
    _Pragma("unroll")                                                           \
    for (int i = 0; i < 4; ++i) {                                               \
      int aoff = i * 4096 + tid * 16;                                           \
      int r_ = aoff >> 7;                                                       \
      int Lb = aoff ^ ((r_ & 7) << 4);                                          \
      gload16(Vp + (size_t)r_ * 1024 + (ktv) + ((Lb & 127) >> 1),               \
              &Vl[i * 2048 + tid * 8]);                                         \
    }                                                                           \
  }

  // per-q-half softmax + PV (sequential halves share one 16-row P buffer)
#define SMAXPV(S, MR, LRN, OA)                                                  \
  {                                                                             \
    float mx = fmaxf(                                                           \
        fmaxf(fmaxf(fmaxf(S[0][0], S[0][1]), fmaxf(S[0][2], S[0][3])),          \
              fmaxf(fmaxf(S[1][0], S[1][1]), fmaxf(S[1][2], S[1][3]))),         \
        fmaxf(fmaxf(fmaxf(S[2][0], S[2][1]), fmaxf(S[2][2], S[2][3])),          \
              fmaxf(fmaxf(S[3][0], S[3][1]), fmaxf(S[3][2], S[3][3]))));        \
    mx = fmaxf(mx, __shfl_xor(mx, 16));                                         \
    mx = fmaxf(mx, __shfl_xor(mx, 32));                                         \
    if (!__all(mx <= MR + 8.0f)) {                                              \
      float mnew = fmaxf(MR, mx);                                               \
      float scq = __builtin_amdgcn_exp2f(MR - mnew);                            \
      MR = mnew;                                                                \
      LRN *= scq;                                                               \
      _Pragma("unroll")                                                         \
      for (int i = 0; i < 4; ++i) {                                             \
        float sco = __shfl(scq, lg * 4 + i);                                    \
        _Pragma("unroll")                                                       \
        for (int dt = 0; dt < 8; ++dt) OA[dt][i] *= sco;                        \
      }                                                                         \
    }                                                                           \
    float p_[4][4];                                                             \
    float ls = 0.f;                                                             \
    _Pragma("unroll")                                                           \
    for (int n = 0; n < 4; ++n) {                                               \
      _Pragma("unroll")                                                         \
      for (int i = 0; i < 4; ++i)                                               \
        p_[n][i] = __builtin_amdgcn_exp2f(S[n][i] - MR);                        \
      ls += (p_[n][0] + p_[n][1]) + (p_[n][2] + p_[n][3]);                      \
    }                                                                           \
    ls += __shfl_xor(ls, 16);                                                   \
    ls += __shfl_xor(ls, 32);                                                   \
    LRN += ls;                                                                  \
    _Pragma("unroll")                                                           \
    for (int n = 0; n < 4; ++n)                                                 \
      _Pragma("unroll")                                                         \
      for (int t2 = 0; t2 < 2; ++t2) {                                          \
        unsigned int u_;                                                        \
        asm("v_cvt_pk_bf16_f32 %0, %1, %2"                                      \
            : "=v"(u_) : "v"(p_[n][2 * t2]), "v"(p_[n][2 * t2 + 1]));           \
        *reinterpret_cast<unsigned int*>(                                       \
            &myP[lr * 76 + n * 16 + lg * 4 + t2 * 2]) = u_;                     \
      }                                                                         \
    bf16x8 pa0_ = *reinterpret_cast<const bf16x8*>(&myP[lr * 76 + lg * 8]);     \
    bf16x8 pa1_ = *reinterpret_cast<const bf16x8*>(&myP[lr * 76 + 32 + lg * 8]);\
    __builtin_amdgcn_s_setprio(1);                                              \
    _Pragma("unroll")                                                           \
    for (int dt = 0; dt < 8; ++dt) {                                            \
      const int rr = dt * 16 + lr;                                              \
      const int rsw_ = (rr & 7) << 4;                                           \
      bf16x8 bv0 = *reinterpret_cast<const bf16x8*>(                            \
          &Vl[(rr * 128 + ((lg * 16) ^ rsw_)) >> 1]);                           \
      bf16x8 bv1 = *reinterpret_cast<const bf16x8*>(                            \
          &Vl[(rr * 128 + ((64 + lg * 16) ^ rsw_)) >> 1]);                      \
      OA[dt] = MFMA16(pa0_, bv0, OA[dt]);                                       \
      OA[dt] = MFMA16(pa1_, bv1, OA[dt]);                                       \
    }                                                                           \
    __builtin_amdgcn_s_setprio(0);                                              \
  }

  f32x4 oacc0[8], oacc1[8];
#pragma unroll
  for (int dt = 0; dt < 8; ++dt) {
    oacc0[dt] = (f32x4){0.f, 0.f, 0.f, 0.f};
    oacc1[dt] = (f32x4){0.f, 0.f, 0.f, 0.f};
  }
  float mrun0 = -3.0e38f, lrun0 = 0.f;
  float mrun1 = -3.0e38f, lrun1 = 0.f;

  STAGE_K(0);
  STAGE_V(0);
  __syncthreads();  // drains vmcnt(0): tile 0 + penalty ready

  for (int t = 0; t < 16; ++t) {
    const int kt = t * 64;

    // ---- S^T = K Q for both q-halves; K frags read once ----
    f32x4 s0[4], s1[4];
    __builtin_amdgcn_s_setprio(1);
#pragma unroll
    for (int n = 0; n < 4; ++n) {
      const int krow = n * 16 + lr;
      const int rsw = (krow & 7) << 4;
      f32x4 a0 = (f32x4){0.f, 0.f, 0.f, 0.f};
      f32x4 a1 = (f32x4){0.f, 0.f, 0.f, 0.f};
#pragma unroll
      for (int c = 0; c < 4; ++c) {
        bf16x8 bk = *reinterpret_cast<const bf16x8*>(
            &Kl[krow * 128 + (((c * 64 + lg * 16) ^ rsw) >> 1)]);
        a0 = MFMA16(bk, aq0[c], a0);
        a1 = MFMA16(bk, aq1[c], a1);
      }
      s0[n] = a0;
      s1[n] = a1;
    }
    __builtin_amdgcn_s_setprio(0);

    __syncthreads();               // all waves done reading Kl (cheap drain)
    if (t < 15) STAGE_K(kt + 64);  // K(t+1) in flight under softmax+PV

    // ---- scale + mask; pen frags shared across halves ----
#pragma unroll
    for (int n = 0; n < 4; ++n) {
      f32x4 pv = *reinterpret_cast<const f32x4*>(&pen[kt + n * 16 + lg * 4]);
#pragma unroll
      for (int i = 0; i < 4; ++i) {
        s0[n][i] = s0[n][i] * SC2 + pv[i];
        s1[n][i] = s1[n][i] * SC2 + pv[i];
      }
    }

    SMAXPV(s0, mrun0, lrun0, oacc0);
    SMAXPV(s1, mrun1, lrun1, oacc1);

    __syncthreads();               // Vl readers done; K loads drained (covered)
    if (t < 15) {
      STAGE_V(kt + 64);            // exposed: L2-hit latency only
      __syncthreads();
    }
  }

  float linv0[4], linv1[4];
#pragma unroll
  for (int i = 0; i < 4; ++i) {
    linv0[i] = 1.0f / __shfl(lrun0, lg * 4 + i);
    linv1[i] = 1.0f / __shfl(lrun1, lg * 4 + i);
  }
#pragma unroll
  for (int dt = 0; dt < 8; ++dt)
#pragma unroll
    for (int i = 0; i < 4; ++i) {
      Op[(size_t)(q0 + lg * 4 + i) * 128 + dt * 16 + lr] =
          f2bf(oacc0[dt][i] * linv0[i]);
      Op[(size_t)(q0 + 16 + lg * 4 + i) * 128 + dt * 16 + lr] =
          f2bf(oacc1[dt][i] * linv1[i]);
    }
#undef STAGE_K
#undef STAGE_V
#undef SMAXPV
}

// ============ Fallback kernels (round-2, 192 MiB workspace) ============
__global__ __launch_bounds__(256) void qkv_proj_old(
    const float* __restrict__ x,
    const float* __restrict__ wq, const float* __restrict__ wk, const float* __restrict__ wv,
    const float* __restrict__ bq, const float* __restrict__ bk, const float* __restrict__ bv,
    unsigned short* __restrict__ Q, unsigned short* __restrict__ K, unsigned short* __restrict__ Vt)
{
  const int tid = threadIdx.x;
  const int wave = tid >> 6, lane = tid & 63;
  const int lr = lane & 15, lg = lane >> 4;
  const int wr = wave >> 1, wc = wave & 1;
  const int mt = blockIdx.x & 7, nt = blockIdx.x >> 3;
  const int b = blockIdx.y, z = blockIdx.z;
  const int l0 = mt * 128, i0 = nt * 128;
  const float* w    = (z == 0) ? wq : (z == 1) ? wk : wv;
  const float* bias = (z == 0) ? bq : (z == 1) ? bk : bv;
  unsigned short* outp = (z == 0) ? Q : (z == 1) ? K : Vt;

  __shared__ __align__(16) unsigned short lA[128 * 40];
  __shared__ __align__(16) unsigned short lB[128 * 40];

  f32x4 acc[4][4];
#pragma unroll
  for (int m = 0; m < 4; ++m)
#pragma unroll
    for (int n = 0; n < 4; ++n) acc[m][n] = (f32x4){0.f, 0.f, 0.f, 0.f};

  const int ad = tid >> 3, aj = tid & 7;
  const int br = tid >> 1, bh2 = tid & 1;

  for (int k0 = 0; k0 < 1024; k0 += 32) {
    const float* xp = x + ((size_t)b * 1024 + k0 + ad) * 1024 + l0;
#pragma unroll
    for (int rep = 0; rep < 4; ++rep) {
      float4 v = *reinterpret_cast<const float4*>(xp + aj * 4 + rep * 32);
      int lb = aj * 4 + rep * 32;
      lA[(lb + 0) * 40 + ad] = f2bf(v.x);
      lA[(lb + 1) * 40 + ad] = f2bf(v.y);
      lA[(lb + 2) * 40 + ad] = f2bf(v.z);
      lA[(lb + 3) * 40 + ad] = f2bf(v.w);
    }
    const float* wp = w + (size_t)(i0 + br) * 1024 + k0 + bh2 * 16;
#pragma unroll
    for (int rep = 0; rep < 4; ++rep) {
      float4 v = *reinterpret_cast<const float4*>(wp + rep * 4);
      int cb = br * 40 + bh2 * 16 + rep * 4;
      lB[cb + 0] = f2bf(v.x); lB[cb + 1] = f2bf(v.y);
      lB[cb + 2] = f2bf(v.z); lB[cb + 3] = f2bf(v.w);
    }
    __syncthreads();
    bf16x8 af[4], bfr[4];
#pragma unroll
    for (int m = 0; m < 4; ++m)
      af[m] = *reinterpret_cast<const bf16x8*>(&lA[(wr * 64 + m * 16 + lr) * 40 + lg * 8]);
#pragma unroll
    for (int n = 0; n < 4; ++n)
      bfr[n] = *reinterpret_cast<const bf16x8*>(&lB[(wc * 64 + n * 16 + lr) * 40 + lg * 8]);
#pragma unroll
    for (int m = 0; m < 4; ++m)
#pragma unroll
      for (int n = 0; n < 4; ++n)
        acc[m][n] = MFMA16(af[m], bfr[n], acc[m][n]);
    __syncthreads();
  }
#pragma unroll
  for (int n = 0; n < 4; ++n) {
    int col = i0 + wc * 64 + n * 16 + lr;
    float bs = bias[col];
    int h = col >> 7, d = col & 127;
#pragma unroll
    for (int m = 0; m < 4; ++m) {
#pragma unroll
      for (int ii = 0; ii < 4; ++ii) {
        int row = l0 + wr * 64 + m * 16 + lg * 4 + ii;
        unsigned short val = f2bf(acc[m][n][ii] + bs);
        if (z < 2)
          outp[(((size_t)b * 8 + h) * 1024 + row) * 128 + d] = val;
        else
          outp[(((size_t)b * 8 + h) * 128 + d) * 1024 + row] = val;
      }
    }
  }
}

__global__ __launch_bounds__(256) void out_proj_old(
    const unsigned short* __restrict__ Obuf, const float* __restrict__ wo,
    const float* __restrict__ bo, float* __restrict__ out)
{
  const int tid = threadIdx.x, wave = tid >> 6, lane = tid & 63;
  const int lr = lane & 15, lg = lane >> 4;
  const int wr = wave >> 1, wc = wave & 1;
  const int mt = blockIdx.x & 7, nt = blockIdx.x >> 3;
  const int b = blockIdx.y;
  const int d0 = mt * 128, l0 = nt * 128;

  __shared__ __align__(16) unsigned short lA[128 * 40];
  __shared__ __align__(16) unsigned short lB[128 * 40];

  f32x4 acc[4][4];
#pragma unroll
  for (int m = 0; m < 4; ++m)
#pragma unroll
    for (int n = 0; n < 4; ++n) acc[m][n] = (f32x4){0.f, 0.f, 0.f, 0.f};

  const int ar = tid >> 1, ah = tid & 1;

  for (int k0 = 0; k0 < 1024; k0 += 32) {
    const float* wp = wo + (size_t)(d0 + ar) * 1024 + k0 + ah * 16;
#pragma unroll
    for (int rep = 0; rep < 4; ++rep) {
      float4 v = *reinterpret_cast<const float4*>(wp + rep * 4);
      int cb = ar * 40 + ah * 16 + rep * 4;
      lA[cb + 0] = f2bf(v.x); lA[cb + 1] = f2bf(v.y);
      lA[cb + 2] = f2bf(v.z); lA[cb + 3] = f2bf(v.w);
    }
    {
      int head = k0 >> 7, dk = (k0 & 127) + ah * 16;
      const unsigned short* op =
          Obuf + (((size_t)b * 8 + head) * 1024 + l0 + ar) * 128 + dk;
#pragma unroll
      for (int rep = 0; rep < 2; ++rep) {
        bf16x8 v = *reinterpret_cast<const bf16x8*>(op + rep * 8);
        *reinterpret_cast<bf16x8*>(&lB[ar * 40 + ah * 16 + rep * 8]) = v;
      }
    }
    __syncthreads();
    bf16x8 af[4], bfr[4];
#pragma unroll
    for (int m = 0; m < 4; ++m)
      af[m] = *reinterpret_cast<const bf16x8*>(&lA[(wr * 64 + m * 16 + lr) * 40 + lg * 8]);
#pragma unroll
    for (int n = 0; n < 4; ++n)
      bfr[n] = *reinterpret_cast<const bf16x8*>(&lB[(wc * 64 + n * 16 + lr) * 40 + lg * 8]);
#pragma unroll
    for (int m = 0; m < 4; ++m)
#pragma unroll
      for (int n = 0; n < 4; ++n)
        acc[m][n] = MFMA16(af[m], bfr[n], acc[m][n]);
    __syncthreads();
  }
#pragma unroll
  for (int m = 0; m < 4; ++m) {
#pragma unroll
    for (int ii = 0; ii < 4; ++ii) {
      int dr = d0 + wr * 64 + m * 16 + lg * 4 + ii;
      float bs = bo[dr];
      float* orow = out + ((size_t)b * 1024 + dr) * 1024 + l0 + wc * 64 + lr;
#pragma unroll
      for (int n = 0; n < 4; ++n)
        orow[n * 16] = acc[m][n][ii] + bs;
    }
  }
}

extern "C" void kernel_launch(void* const* d_in, const int* in_sizes, int n_in,
                              void* d_out, int out_size, void* d_ws, size_t ws_size,
                              hipStream_t stream) {
  const float* x  = (const float*)d_in[0];
  const int* mask = (const int*)d_in[1];
  const float* wq = (const float*)d_in[2];
  const float* bq = (const float*)d_in[3];
  const float* wk = (const float*)d_in[4];
  const float* bk = (const float*)d_in[5];
  const float* wv = (const float*)d_in[6];
  const float* bv = (const float*)d_in[7];
  const float* wo = (const float*)d_in[8];
  const float* bo = (const float*)d_in[9];
  float* out = (float*)d_out;

  const size_t MB64 = (size_t)64 << 20;
  const size_t NEED = (size_t)264 << 20;

  if (ws_size >= NEED) {
    unsigned short* xT   = (unsigned short*)d_ws;
    unsigned short* Q    = (unsigned short*)((char*)d_ws + MB64);
    unsigned short* K    = (unsigned short*)((char*)d_ws + 2 * MB64);
    unsigned short* Vt   = (unsigned short*)((char*)d_ws + 3 * MB64);
    unsigned short* Wqkv = (unsigned short*)((char*)d_ws + 4 * MB64);
    unsigned short* Wo   = Wqkv + (size_t)3 * 1048576;

    x_transpose<<<dim3(16, 16, 32), 256, 0, stream>>>(x, xT);
    w_convert<<<dim3(1024, 4), 256, 0, stream>>>(wq, wk, wv, wo, Wqkv, Wo);
    qkv_gemm8<<<dim3(1536), 512, 0, stream>>>(xT, Wqkv, bq, bk, bv, Q, K, Vt);
    flash_attn<<<dim3(2048), 256, 0, stream>>>(Q, K, Vt, mask, Q);
    out_gemm8<<<dim3(16, 32), 512, 0, stream>>>(Wo, Q, bo, out);
  } else {
    unsigned short* Q  = (unsigned short*)d_ws;
    unsigned short* K  = Q + (size_t)33554432;
    unsigned short* Vt = K + (size_t)33554432;
    qkv_proj_old<<<dim3(64, 32, 3), 256, 0, stream>>>(x, wq, wk, wv, bq, bk, bv, Q, K, Vt);
    flash_attn<<<dim3(2048), 256, 0, stream>>>(Q, K, Vt, mask, Q);
    out_proj_old<<<dim3(64, 32), 256, 0, stream>>>(Q, wo, bo, out);
  }
}

// Round 11
// 590.050 us; speedup vs baseline: 1.2879x; 1.2879x over previous
//
#include <hip/hip_runtime.h>
#include <hip/hip_bf16.h>

typedef __bf16 bf16_t;
typedef bf16_t bf16x8 __attribute__((ext_vector_type(8)));
typedef float f32x4 __attribute__((ext_vector_type(4)));

#define MFMA16(a, b, c) __builtin_amdgcn_mfma_f32_16x16x32_bf16(a, b, c, 0, 0, 0)
#define NEGV -1e30f

__device__ __forceinline__ unsigned short f2bf(float f) {
  union { float f; unsigned int u; } v; v.f = f;
  unsigned int r = v.u + 0x7FFFu + ((v.u >> 16) & 1u);
  return (unsigned short)(r >> 16);
}

__device__ __forceinline__ void gload16(const unsigned short* g, unsigned short* l) {
  __builtin_amdgcn_global_load_lds(
      (const __attribute__((address_space(1))) void*)g,
      (__attribute__((address_space(3))) void*)l, 16, 0, 0);
}

// ============ Kernel P1: x [B,D,L] fp32 -> xT [B,L,D] bf16 ============
__global__ __launch_bounds__(256) void x_transpose(
    const float* __restrict__ x, unsigned short* __restrict__ xT)
{
  const int b = blockIdx.z;
  const int l0 = blockIdx.x * 64, d0 = blockIdx.y * 64;
  __shared__ __align__(16) unsigned short T[64][68];
  const int tid = threadIdx.x;
  const int dl = tid >> 4, lc = (tid & 15) * 4;
#pragma unroll
  for (int rep = 0; rep < 4; ++rep) {
    int d = dl + rep * 16;
    float4 v = *reinterpret_cast<const float4*>(
        x + ((size_t)b * 1024 + d0 + d) * 1024 + l0 + lc);
    ushort4 u;
    u.x = f2bf(v.x); u.y = f2bf(v.y); u.z = f2bf(v.z); u.w = f2bf(v.w);
    *reinterpret_cast<ushort4*>(&T[d][lc]) = u;
  }
  __syncthreads();
  const int dbase = (tid & 15) * 4, lbase = (tid >> 4) * 4;
  ushort4 r0 = *reinterpret_cast<const ushort4*>(&T[dbase + 0][lbase]);
  ushort4 r1 = *reinterpret_cast<const ushort4*>(&T[dbase + 1][lbase]);
  ushort4 r2 = *reinterpret_cast<const ushort4*>(&T[dbase + 2][lbase]);
  ushort4 r3 = *reinterpret_cast<const ushort4*>(&T[dbase + 3][lbase]);
  ushort4 w0 = {r0.x, r1.x, r2.x, r3.x};
  ushort4 w1 = {r0.y, r1.y, r2.y, r3.y};
  ushort4 w2 = {r0.z, r1.z, r2.z, r3.z};
  ushort4 w3 = {r0.w, r1.w, r2.w, r3.w};
  unsigned short* op = xT + ((size_t)b * 1024 + l0 + lbase) * 1024 + d0 + dbase;
  *reinterpret_cast<ushort4*>(op) = w0;
  *reinterpret_cast<ushort4*>(op + 1024) = w1;
  *reinterpret_cast<ushort4*>(op + 2048) = w2;
  *reinterpret_cast<ushort4*>(op + 3072) = w3;
}

// ============ Kernel P2: weights fp32 -> bf16 (Wqkv concat + Wo) ============
__global__ __launch_bounds__(256) void w_convert(
    const float* __restrict__ wq, const float* __restrict__ wk,
    const float* __restrict__ wv, const float* __restrict__ wo,
    unsigned short* __restrict__ Wqkv, unsigned short* __restrict__ Wo)
{
  const int z = blockIdx.y;
  const float* src = (z == 0) ? wq : (z == 1) ? wk : (z == 2) ? wv : wo;
  unsigned short* dst = (z < 3) ? Wqkv + (size_t)z * 1048576 : Wo;
  size_t off = ((size_t)blockIdx.x * 256 + threadIdx.x) * 4;
  float4 v = *reinterpret_cast<const float4*>(src + off);
  ushort4 u = {f2bf(v.x), f2bf(v.y), f2bf(v.z), f2bf(v.w)};
  *reinterpret_cast<ushort4*>(dst + off) = u;
}

// ============ Kernel A: fused QKV GEMM — 256^2 / BK64, 8-phase counted-vmcnt ==
__global__ __launch_bounds__(512, 2) void qkv_gemm8(
    const unsigned short* __restrict__ xT, const unsigned short* __restrict__ Wqkv,
    const float* __restrict__ bq, const float* __restrict__ bk, const float* __restrict__ bv,
    unsigned short* __restrict__ Q, unsigned short* __restrict__ K,
    unsigned short* __restrict__ Vt)
{
  __shared__ __align__(16) unsigned short lds[2][4][8192];  // 128 KiB

  const int tid = threadIdx.x;
  const int wave = tid >> 6, lane = tid & 63;
  const int lr = lane & 15, lg = lane >> 4;
  const int wr = wave >> 2, wc = wave & 3;

  const int bid = blockIdx.x;
  const int swz = (bid & 7) * 192 + (bid >> 3);  // 1536 % 8 == 0: bijective
  const int mt = swz / 12, nt = swz % 12;
  const int m0 = mt * 256, n0 = nt * 256;

  const unsigned short* Ag = xT + (size_t)m0 * 1024;
  const unsigned short* Bg = Wqkv + (size_t)n0 * 1024;

  const int srow = tid >> 2;
  const int schk = (tid & 3) * 8;

#define STAGE_HT(BUF, REG, TI)                                                 \
  {                                                                            \
    const int kt_ = ((TI) < 16 ? (TI) : 15) * 64 + (((REG)&1) * 32) + schk;    \
    const unsigned short* gp_ = (((REG) < 2) ? Ag : Bg);                       \
    _Pragma("unroll")                                                          \
    for (int j_ = 0; j_ < 2; ++j_)                                             \
      gload16(gp_ + (size_t)(j_ * 128 + srow) * 1024 + kt_,                    \
              &lds[BUF][REG][j_ * 4096 + tid * 8]);                            \
  }

#define LDA(BUF, KK, MH, AR)                                                   \
  _Pragma("unroll")                                                            \
  for (int mi_ = 0; mi_ < 4; ++mi_)                                            \
    AR[mi_] = *reinterpret_cast<const bf16x8*>(                                \
        &lds[BUF][KK][(wr * 128 + (MH)*64 + mi_ * 16 + lr) * 32 + lg * 8]);

#define LDB(BUF, KK, BR)                                                       \
  _Pragma("unroll")                                                            \
  for (int n_ = 0; n_ < 4; ++n_)                                               \
    BR[n_] = *reinterpret_cast<const bf16x8*>(                                 \
        &lds[BUF][2 + (KK)][(wc * 64 + n_ * 16 + lr) * 32 + lg * 8]);

#define MM(AR, BR, MH)                                                         \
  __builtin_amdgcn_s_setprio(1);                                               \
  _Pragma("unroll")                                                            \
  for (int mi_ = 0; mi_ < 4; ++mi_)                                            \
    _Pragma("unroll")                                                          \
    for (int n_ = 0; n_ < 4; ++n_)                                             \
      acc[(MH)*4 + mi_][n_] = MFMA16(AR[mi_], BR[n_], acc[(MH)*4 + mi_][n_]);  \
  __builtin_amdgcn_s_setprio(0);

#define BAR()                                                                  \
  {                                                                            \
    asm volatile("" ::: "memory");                                             \
    __builtin_amdgcn_s_barrier();                                              \
    asm volatile("" ::: "memory");                                             \
  }
#define VMW() asm volatile("s_waitcnt vmcnt(10)" ::: "memory")

  f32x4 acc[8][4];
#pragma unroll
  for (int m = 0; m < 8; ++m)
#pragma unroll
    for (int n = 0; n < 4; ++n) acc[m][n] = (f32x4){0.f, 0.f, 0.f, 0.f};

  STAGE_HT(0, 2, 0); STAGE_HT(0, 0, 0); STAGE_HT(0, 3, 0); STAGE_HT(0, 1, 0);
  STAGE_HT(1, 2, 1); STAGE_HT(1, 0, 1); STAGE_HT(1, 3, 1);
  VMW();
  BAR();

  for (int it = 0; it < 8; ++it) {
    const int T = 2 * it;
    bf16x8 a0[4], a1[4], b0[4], b1[4];
    LDB(0, 0, b0); LDA(0, 0, 0, a0);
    STAGE_HT(1, 1, T + 1);
    BAR();
    MM(a0, b0, 0);
    BAR();
    LDA(0, 0, 1, a1);
    STAGE_HT(0, 2, T + 2);
    BAR();
    MM(a1, b0, 1);
    VMW(); BAR();
    LDB(0, 1, b1); LDA(0, 1, 0, a0);
    STAGE_HT(0, 0, T + 2);
    BAR();
    MM(a0, b1, 0);
    BAR();
    LDA(0, 1, 1, a1);
    STAGE_HT(0, 3, T + 2);
    BAR();
    MM(a1, b1, 1);
    VMW(); BAR();
    LDB(1, 0, b0); LDA(1, 0, 0, a0);
    STAGE_HT(0, 1, T + 2);
    BAR();
    MM(a0, b0, 0);
    BAR();
    LDA(1, 0, 1, a1);
    STAGE_HT(1, 2, T + 3);
    BAR();
    MM(a1, b0, 1);
    VMW(); BAR();
    LDB(1, 1, b1); LDA(1, 1, 0, a0);
    STAGE_HT(1, 0, T + 3);
    BAR();
    MM(a0, b1, 0);
    BAR();
    LDA(1, 1, 1, a1);
    STAGE_HT(1, 3, T + 3);
    BAR();
    MM(a1, b1, 1);
    VMW(); BAR();
  }

  const int zi = n0 >> 10;
  const float* bias = (zi == 0) ? bq : (zi == 1) ? bk : bv;
  const int b = m0 >> 10;
  const int lbase = (m0 & 1023) + wr * 128;

  if (zi < 2) {
    unsigned short* op = ((zi == 0) ? Q : K);
#pragma unroll
    for (int n = 0; n < 4; ++n) {
      const int col = (n0 & 1023) + wc * 64 + n * 16 + lr;
      const int h = col >> 7, d = col & 127;
      const float bs = bias[col];
      unsigned short* hp = op + ((size_t)b * 8 + h) * 131072 + d;
#pragma unroll
      for (int m = 0; m < 8; ++m)
#pragma unroll
        for (int ii = 0; ii < 4; ++ii) {
          int l = lbase + m * 16 + lg * 4 + ii;
          hp[(size_t)l * 128] = f2bf(acc[m][n][ii] + bs);
        }
    }
  } else {
#pragma unroll
    for (int n = 0; n < 4; ++n) {
      const int col = (n0 & 1023) + wc * 64 + n * 16 + lr;
      const int h = col >> 7, d = col & 127;
      const float bs = bias[col];
      unsigned short* hp = Vt + ((size_t)b * 8 + h) * 131072 + (size_t)d * 1024;
#pragma unroll
      for (int m = 0; m < 8; ++m) {
        int l = lbase + m * 16 + lg * 4;
        ushort4 u = {f2bf(acc[m][n][0] + bs), f2bf(acc[m][n][1] + bs),
                     f2bf(acc[m][n][2] + bs), f2bf(acc[m][n][3] + bs)};
        *reinterpret_cast<ushort4*>(&hp[l]) = u;
      }
    }
  }
#undef STAGE_HT
}

// ============ Kernel C: out projection — 256^2 / BK64, 8-phase ============
__global__ __launch_bounds__(512, 2) void out_gemm8(
    const unsigned short* __restrict__ Wo, const unsigned short* __restrict__ O,
    const float* __restrict__ bo, float* __restrict__ out)
{
  __shared__ __align__(16) unsigned short lds[2][4][8192];

  const int tid = threadIdx.x;
  const int wave = tid >> 6, lane = tid & 63;
  const int lr = lane & 15, lg = lane >> 4;
  const int wr = wave >> 2, wc = wave & 3;

  const int b = blockIdx.y;
  const int bid = blockIdx.x;                  // 16 tiles per batch
  const int swz = (bid & 7) * 2 + (bid >> 3);  // bijective (16 % 8 == 0)
  const int mt = swz >> 2, nt = swz & 3;
  const int d0 = mt * 256, l0 = nt * 256;

  const unsigned short* Ag = Wo + (size_t)d0 * 1024;
  const unsigned short* Og = O + (size_t)b * 8 * 131072;

  const int srow = tid >> 2;
  const int schk = (tid & 3) * 8;

#define STAGE_HT(BUF, REG, TI)                                                 \
  {                                                                            \
    const int kt_ = ((TI) < 16 ? (TI) : 15) * 64 + (((REG)&1) * 32) + schk;    \
    if ((REG) < 2) {                                                           \
      _Pragma("unroll")                                                        \
      for (int j_ = 0; j_ < 2; ++j_)                                           \
        gload16(Ag + (size_t)(j_ * 128 + srow) * 1024 + kt_,                   \
                &lds[BUF][REG][j_ * 4096 + tid * 8]);                          \
    } else {                                                                   \
      const int h_ = kt_ >> 7, dk_ = kt_ & 127;                                \
      _Pragma("unroll")                                                        \
      for (int j_ = 0; j_ < 2; ++j_)                                           \
        gload16(Og + (size_t)h_ * 131072 +                                     \
                    (size_t)(l0 + j_ * 128 + srow) * 128 + dk_,                \
                &lds[BUF][REG][j_ * 4096 + tid * 8]);                          \
    }                                                                          \
  }

  f32x4 acc[8][4];
#pragma unroll
  for (int m = 0; m < 8; ++m)
#pragma unroll
    for (int n = 0; n < 4; ++n) acc[m][n] = (f32x4){0.f, 0.f, 0.f, 0.f};

  STAGE_HT(0, 2, 0); STAGE_HT(0, 0, 0); STAGE_HT(0, 3, 0); STAGE_HT(0, 1, 0);
  STAGE_HT(1, 2, 1); STAGE_HT(1, 0, 1); STAGE_HT(1, 3, 1);
  VMW();
  BAR();

  for (int it = 0; it < 8; ++it) {
    const int T = 2 * it;
    bf16x8 a0[4], a1[4], b0[4], b1[4];
    LDB(0, 0, b0); LDA(0, 0, 0, a0);
    STAGE_HT(1, 1, T + 1);
    BAR();
    MM(a0, b0, 0);
    BAR();
    LDA(0, 0, 1, a1);
    STAGE_HT(0, 2, T + 2);
    BAR();
    MM(a1, b0, 1);
    VMW(); BAR();
    LDB(0, 1, b1); LDA(0, 1, 0, a0);
    STAGE_HT(0, 0, T + 2);
    BAR();
    MM(a0, b1, 0);
    BAR();
    LDA(0, 1, 1, a1);
    STAGE_HT(0, 3, T + 2);
    BAR();
    MM(a1, b1, 1);
    VMW(); BAR();
    LDB(1, 0, b0); LDA(1, 0, 0, a0);
    STAGE_HT(0, 1, T + 2);
    BAR();
    MM(a0, b0, 0);
    BAR();
    LDA(1, 0, 1, a1);
    STAGE_HT(1, 2, T + 3);
    BAR();
    MM(a1, b0, 1);
    VMW(); BAR();
    LDB(1, 1, b1); LDA(1, 1, 0, a0);
    STAGE_HT(1, 0, T + 3);
    BAR();
    MM(a0, b1, 0);
    BAR();
    LDA(1, 1, 1, a1);
    STAGE_HT(1, 3, T + 3);
    BAR();
    MM(a1, b1, 1);
    VMW(); BAR();
  }

#pragma unroll
  for (int m = 0; m < 8; ++m) {
#pragma unroll
    for (int ii = 0; ii < 4; ++ii) {
      int dr = d0 + wr * 128 + m * 16 + lg * 4 + ii;
      float bs = bo[dr];
      float* orow = out + ((size_t)b * 1024 + dr) * 1024 + l0 + wc * 64 + lr;
#pragma unroll
      for (int n = 0; n < 4; ++n)
        orow[n * 16] = acc[m][n][ii] + bs;
    }
  }
#undef STAGE_HT
#undef LDA
#undef LDB
#undef MM
#undef BAR
#undef VMW
}

// ============ Kernel B: flash attention — QBLK=32/wave, KVBLK=64 ============
// R9-good structure (double-buffered gload_lds, 2 blocks/CU, XCD 1D grid) +
// interleaved dual-half softmax: both halves' max/exp/sum chains in one basic
// block (2x ILP on serial spines), then pack-P0/PV0, pack-P1/PV1.
__global__ __launch_bounds__(256, 2) void flash_attn(
    const unsigned short* __restrict__ Q, const unsigned short* __restrict__ Kb,
    const unsigned short* __restrict__ Vt, const int* __restrict__ mask,
    unsigned short* __restrict__ O)
{
  const int tid = threadIdx.x, wave = tid >> 6, lane = tid & 63;
  const int lr = lane & 15, lg = lane >> 4;
  const int id = blockIdx.x;
  const int qt = (id >> 3) & 7;
  const int bh_ = ((id >> 6) << 3) | (id & 7);
  const int b = bh_ >> 3;
  const size_t bh = (size_t)bh_;
  const unsigned short* Qp = Q + bh * 131072;
  const unsigned short* Kp = Kb + bh * 131072;
  const unsigned short* Vp = Vt + bh * 131072;
  unsigned short* Op = O + bh * 131072;
  const int q0 = qt * 128 + wave * 32;
  const float SC2 = 0.12751744f;        // (1/sqrt(128)) * log2(e)
  const float NEG2 = -1.442695e30f;     // -1e30 * log2(e)

  __shared__ __align__(16) unsigned short Kl[2][64 * 128];   // 2 x 16 KiB
  __shared__ __align__(16) unsigned short Vl[2][128 * 64];   // 2 x 16 KiB
  __shared__ __align__(16) unsigned short plds[4][16 * 76];  // 9.5 KiB
  __shared__ float pen[1024];                                // 4 KiB

  {
    const int4 mv = *reinterpret_cast<const int4*>(mask + b * 1024 + tid * 4);
    float4 pv;
    pv.x = mv.x ? NEG2 : 0.f; pv.y = mv.y ? NEG2 : 0.f;
    pv.z = mv.z ? NEG2 : 0.f; pv.w = mv.w ? NEG2 : 0.f;
    *reinterpret_cast<float4*>(&pen[tid * 4]) = pv;
  }

  unsigned short* myP = plds[wave];

  bf16x8 aq0[4], aq1[4];
#pragma unroll
  for (int c = 0; c < 4; ++c) {
    aq0[c] = *reinterpret_cast<const bf16x8*>(
        &Qp[(size_t)(q0 + lr) * 128 + c * 32 + lg * 8]);
    aq1[c] = *reinterpret_cast<const bf16x8*>(
        &Qp[(size_t)(q0 + 16 + lr) * 128 + c * 32 + lg * 8]);
  }

  // K: [64][128] rows 256B, byte ^= (row&7)<<4. V: [128][64] rows 128B, same XOR.
#define STAGE(bufi, ktv)                                                        \
  {                                                                             \
    _Pragma("unroll")                                                           \
    for (int i = 0; i < 4; ++i) {                                               \
      int krow = i * 16 + (tid >> 4);                                           \
      int kcb = ((tid & 15) * 16) ^ ((krow & 7) << 4);                          \
      gload16(Kp + (size_t)((ktv) + krow) * 128 + (kcb >> 1),                   \
              &Kl[bufi][i * 2048 + tid * 8]);                                   \
      int aoff = i * 4096 + tid * 16;                                           \
      int r_ = aoff >> 7;                                                       \
      int Lb = aoff ^ ((r_ & 7) << 4);                                          \
      gload16(Vp + (size_t)r_ * 1024 + (ktv) + ((Lb & 127) >> 1),               \
              &Vl[bufi][i * 2048 + tid * 8]);                                   \
    }                                                                           \
  }

  // pack one half's P into myP and run its PV MFMA cluster
#define PACKPV(P, OA)                                                           \
  {                                                                             \
    _Pragma("unroll")                                                           \
    for (int n = 0; n < 4; ++n)                                                 \
      _Pragma("unroll")                                                         \
      for (int t2 = 0; t2 < 2; ++t2) {                                          \
        unsigned int u_;                                                        \
        asm("v_cvt_pk_bf16_f32 %0, %1, %2"                                      \
            : "=v"(u_) : "v"(P[n][2 * t2]), "v"(P[n][2 * t2 + 1]));             \
        *reinterpret_cast<unsigned int*>(                                       \
            &myP[lr * 76 + n * 16 + lg * 4 + t2 * 2]) = u_;                     \
      }                                                                         \
    bf16x8 pa0_ = *reinterpret_cast<const bf16x8*>(&myP[lr * 76 + lg * 8]);     \
    bf16x8 pa1_ = *reinterpret_cast<const bf16x8*>(&myP[lr * 76 + 32 + lg * 8]);\
    __builtin_amdgcn_s_setprio(1);                                              \
    _Pragma("unroll")                                                           \
    for (int dt = 0; dt < 8; ++dt) {                                            \
      const int rr = dt * 16 + lr;                                              \
      const int rsw_ = (rr & 7) << 4;                                           \
      bf16x8 bv0 = *reinterpret_cast<const bf16x8*>(                            \
          &Vl[cur][(rr * 128 + ((lg * 16) ^ rsw_)) >> 1]);                      \
      bf16x8 bv1 = *reinterpret_cast<const bf16x8*>(                            \
          &Vl[cur][(rr * 128 + ((64 + lg * 16) ^ rsw_)) >> 1]);                 \
      OA[dt] = MFMA16(pa0_, bv0, OA[dt]);                                       \
      OA[dt] = MFMA16(pa1_, bv1, OA[dt]);                                       \
    }                                                                           \
    __builtin_amdgcn_s_setprio(0);                                              \
  }

  f32x4 oacc0[8], oacc1[8];
#pragma unroll
  for (int dt = 0; dt < 8; ++dt) {
    oacc0[dt] = (f32x4){0.f, 0.f, 0.f, 0.f};
    oacc1[dt] = (f32x4){0.f, 0.f, 0.f, 0.f};
  }
  float mrun0 = -3.0e38f, lrun0 = 0.f;
  float mrun1 = -3.0e38f, lrun1 = 0.f;

  STAGE(0, 0);
  __syncthreads();

  int cur = 0;
  for (int t = 0; t < 16; ++t) {
    const int kt = t * 64;
    if (t < 15) STAGE(cur ^ 1, kt + 64);

    // ---- S^T = K Q for both q-halves; K frags read once ----
    f32x4 s0[4], s1[4];
    __builtin_amdgcn_s_setprio(1);
#pragma unroll
    for (int n = 0; n < 4; ++n) {
      const int krow = n * 16 + lr;
      const int rsw = (krow & 7) << 4;
      f32x4 a0 = (f32x4){0.f, 0.f, 0.f, 0.f};
      f32x4 a1 = (f32x4){0.f, 0.f, 0.f, 0.f};
#pragma unroll
      for (int c = 0; c < 4; ++c) {
        bf16x8 bk = *reinterpret_cast<const bf16x8*>(
            &Kl[cur][krow * 128 + (((c * 64 + lg * 16) ^ rsw) >> 1)]);
        a0 = MFMA16(bk, aq0[c], a0);
        a1 = MFMA16(bk, aq1[c], a1);
      }
      s0[n] = a0;
      s1[n] = a1;
    }
    __builtin_amdgcn_s_setprio(0);

    // ---- scale + mask; pen frags shared across halves ----
#pragma unroll
    for (int n = 0; n < 4; ++n) {
      f32x4 pv = *reinterpret_cast<const f32x4*>(&pen[kt + n * 16 + lg * 4]);
#pragma unroll
      for (int i = 0; i < 4; ++i) {
        s0[n][i] = s0[n][i] * SC2 + pv[i];
        s1[n][i] = s1[n][i] * SC2 + pv[i];
      }
    }

    // ---- interleaved dual-half softmax (independent chains, 2x ILP) ----
    float mx0 = fmaxf(
        fmaxf(fmaxf(fmaxf(s0[0][0], s0[0][1]), fmaxf(s0[0][2], s0[0][3])),
              fmaxf(fmaxf(s0[1][0], s0[1][1]), fmaxf(s0[1][2], s0[1][3]))),
        fmaxf(fmaxf(fmaxf(s0[2][0], s0[2][1]), fmaxf(s0[2][2], s0[2][3])),
              fmaxf(fmaxf(s0[3][0], s0[3][1]), fmaxf(s0[3][2], s0[3][3]))));
    float mx1 = fmaxf(
        fmaxf(fmaxf(fmaxf(s1[0][0], s1[0][1]), fmaxf(s1[0][2], s1[0][3])),
              fmaxf(fmaxf(s1[1][0], s1[1][1]), fmaxf(s1[1][2], s1[1][3]))),
        fmaxf(fmaxf(fmaxf(s1[2][0], s1[2][1]), fmaxf(s1[2][2], s1[2][3])),
              fmaxf(fmaxf(s1[3][0], s1[3][1]), fmaxf(s1[3][2], s1[3][3]))));
    mx0 = fmaxf(mx0, __shfl_xor(mx0, 16));
    mx1 = fmaxf(mx1, __shfl_xor(mx1, 16));
    mx0 = fmaxf(mx0, __shfl_xor(mx0, 32));
    mx1 = fmaxf(mx1, __shfl_xor(mx1, 32));

    if (!__all(mx0 <= mrun0 + 8.0f)) {
      float mnew = fmaxf(mrun0, mx0);
      float scq = __builtin_amdgcn_exp2f(mrun0 - mnew);
      mrun0 = mnew;
      lrun0 *= scq;
#pragma unroll
      for (int i = 0; i < 4; ++i) {
        float sco = __shfl(scq, lg * 4 + i);
#pragma unroll
        for (int dt = 0; dt < 8; ++dt) oacc0[dt][i] *= sco;
      }
    }
    if (!__all(mx1 <= mrun1 + 8.0f)) {
      float mnew = fmaxf(mrun1, mx1);
      float scq = __builtin_amdgcn_exp2f(mrun1 - mnew);
      mrun1 = mnew;
      lrun1 *= scq;
#pragma unroll
      for (int i = 0; i < 4; ++i) {
        float sco = __shfl(scq, lg * 4 + i);
#pragma unroll
        for (int dt = 0; dt < 8; ++dt) oacc1[dt][i] *= sco;
      }
    }

    float p0[4][4], p1[4][4];
    float ls0 = 0.f, ls1 = 0.f;
#pragma unroll
    for (int n = 0; n < 4; ++n) {
#pragma unroll
      for (int i = 0; i < 4; ++i) {
        p0[n][i] = __builtin_amdgcn_exp2f(s0[n][i] - mrun0);
        p1[n][i] = __builtin_amdgcn_exp2f(s1[n][i] - mrun1);
      }
      ls0 += (p0[n][0] + p0[n][1]) + (p0[n][2] + p0[n][3]);
      ls1 += (p1[n][0] + p1[n][1]) + (p1[n][2] + p1[n][3]);
    }
    ls0 += __shfl_xor(ls0, 16);
    ls1 += __shfl_xor(ls1, 16);
    ls0 += __shfl_xor(ls0, 32);
    ls1 += __shfl_xor(ls1, 32);
    lrun0 += ls0;
    lrun1 += ls1;

    // ---- PV: half 0 then half 1 (myP reuse safe: same-wave DS ordering) ----
    PACKPV(p0, oacc0);
    PACKPV(p1, oacc1);

    __syncthreads();
    cur ^= 1;
  }

  float linv0[4], linv1[4];
#pragma unroll
  for (int i = 0; i < 4; ++i) {
    linv0[i] = 1.0f / __shfl(lrun0, lg * 4 + i);
    linv1[i] = 1.0f / __shfl(lrun1, lg * 4 + i);
  }
#pragma unroll
  for (int dt = 0; dt < 8; ++dt)
#pragma unroll
    for (int i = 0; i < 4; ++i) {
      Op[(size_t)(q0 + lg * 4 + i) * 128 + dt * 16 + lr] =
          f2bf(oacc0[dt][i] * linv0[i]);
      Op[(size_t)(q0 + 16 + lg * 4 + i) * 128 + dt * 16 + lr] =
          f2bf(oacc1[dt][i] * linv1[i]);
    }
#undef STAGE
#undef PACKPV
}

// ============ Fallback kernels (round-2, 192 MiB workspace) ============
__global__ __launch_bounds__(256) void qkv_proj_old(
    const float* __restrict__ x,
    const float* __restrict__ wq, const float* __restrict__ wk, const float* __restrict__ wv,
    const float* __restrict__ bq, const float* __restrict__ bk, const float* __restrict__ bv,
    unsigned short* __restrict__ Q, unsigned short* __restrict__ K, unsigned short* __restrict__ Vt)
{
  const int tid = threadIdx.x;
  const int wave = tid >> 6, lane = tid & 63;
  const int lr = lane & 15, lg = lane >> 4;
  const int wr = wave >> 1, wc = wave & 1;
  const int mt = blockIdx.x & 7, nt = blockIdx.x >> 3;
  const int b = blockIdx.y, z = blockIdx.z;
  const int l0 = mt * 128, i0 = nt * 128;
  const float* w    = (z == 0) ? wq : (z == 1) ? wk : wv;
  const float* bias = (z == 0) ? bq : (z == 1) ? bk : bv;
  unsigned short* outp = (z == 0) ? Q : (z == 1) ? K : Vt;

  __shared__ __align__(16) unsigned short lA[128 * 40];
  __shared__ __align__(16) unsigned short lB[128 * 40];

  f32x4 acc[4][4];
#pragma unroll
  for (int m = 0; m < 4; ++m)
#pragma unroll
    for (int n = 0; n < 4; ++n) acc[m][n] = (f32x4){0.f, 0.f, 0.f, 0.f};

  const int ad = tid >> 3, aj = tid & 7;
  const int br = tid >> 1, bh2 = tid & 1;

  for (int k0 = 0; k0 < 1024; k0 += 32) {
    const float* xp = x + ((size_t)b * 1024 + k0 + ad) * 1024 + l0;
#pragma unroll
    for (int rep = 0; rep < 4; ++rep) {
      float4 v = *reinterpret_cast<const float4*>(xp + aj * 4 + rep * 32);
      int lb = aj * 4 + rep * 32;
      lA[(lb + 0) * 40 + ad] = f2bf(v.x);
      lA[(lb + 1) * 40 + ad] = f2bf(v.y);
      lA[(lb + 2) * 40 + ad] = f2bf(v.z);
      lA[(lb + 3) * 40 + ad] = f2bf(v.w);
    }
    const float* wp = w + (size_t)(i0 + br) * 1024 + k0 + bh2 * 16;
#pragma unroll
    for (int rep = 0; rep < 4; ++rep) {
      float4 v = *reinterpret_cast<const float4*>(wp + rep * 4);
      int cb = br * 40 + bh2 * 16 + rep * 4;
      lB[cb + 0] = f2bf(v.x); lB[cb + 1] = f2bf(v.y);
      lB[cb + 2] = f2bf(v.z); lB[cb + 3] = f2bf(v.w);
    }
    __syncthreads();
    bf16x8 af[4], bfr[4];
#pragma unroll
    for (int m = 0; m < 4; ++m)
      af[m] = *reinterpret_cast<const bf16x8*>(&lA[(wr * 64 + m * 16 + lr) * 40 + lg * 8]);
#pragma unroll
    for (int n = 0; n < 4; ++n)
      bfr[n] = *reinterpret_cast<const bf16x8*>(&lB[(wc * 64 + n * 16 + lr) * 40 + lg * 8]);
#pragma unroll
    for (int m = 0; m < 4; ++m)
#pragma unroll
      for (int n = 0; n < 4; ++n)
        acc[m][n] = MFMA16(af[m], bfr[n], acc[m][n]);
    __syncthreads();
  }
#pragma unroll
  for (int n = 0; n < 4; ++n) {
    int col = i0 + wc * 64 + n * 16 + lr;
    float bs = bias[col];
    int h = col >> 7, d = col & 127;
#pragma unroll
    for (int m = 0; m < 4; ++m) {
#pragma unroll
      for (int ii = 0; ii < 4; ++ii) {
        int row = l0 + wr * 64 + m * 16 + lg * 4 + ii;
        unsigned short val = f2bf(acc[m][n][ii] + bs);
        if (z < 2)
          outp[(((size_t)b * 8 + h) * 1024 + row) * 128 + d] = val;
        else
          outp[(((size_t)b * 8 + h) * 128 + d) * 1024 + row] = val;
      }
    }
  }
}

__global__ __launch_bounds__(256) void out_proj_old(
    const unsigned short* __restrict__ Obuf, const float* __restrict__ wo,
    const float* __restrict__ bo, float* __restrict__ out)
{
  const int tid = threadIdx.x, wave = tid >> 6, lane = tid & 63;
  const int lr = lane & 15, lg = lane >> 4;
  const int wr = wave >> 1, wc = wave & 1;
  const int mt = blockIdx.x & 7, nt = blockIdx.x >> 3;
  const int b = blockIdx.y;
  const int d0 = mt * 128, l0 = nt * 128;

  __shared__ __align__(16) unsigned short lA[128 * 40];
  __shared__ __align__(16) unsigned short lB[128 * 40];

  f32x4 acc[4][4];
#pragma unroll
  for (int m = 0; m < 4; ++m)
#pragma unroll
    for (int n = 0; n < 4; ++n) acc[m][n] = (f32x4){0.f, 0.f, 0.f, 0.f};

  const int ar = tid >> 1, ah = tid & 1;

  for (int k0 = 0; k0 < 1024; k0 += 32) {
    const float* wp = wo + (size_t)(d0 + ar) * 1024 + k0 + ah * 16;
#pragma unroll
    for (int rep = 0; rep < 4; ++rep) {
      float4 v = *reinterpret_cast<const float4*>(wp + rep * 4);
      int cb = ar * 40 + ah * 16 + rep * 4;
      lA[cb + 0] = f2bf(v.x); lA[cb + 1] = f2bf(v.y);
      lA[cb + 2] = f2bf(v.z); lA[cb + 3] = f2bf(v.w);
    }
    {
      int head = k0 >> 7, dk = (k0 & 127) + ah * 16;
      const unsigned short* op =
          Obuf + (((size_t)b * 8 + head) * 1024 + l0 + ar) * 128 + dk;
#pragma unroll
      for (int rep = 0; rep < 2; ++rep) {
        bf16x8 v = *reinterpret_cast<const bf16x8*>(op + rep * 8);
        *reinterpret_cast<bf16x8*>(&lB[ar * 40 + ah * 16 + rep * 8]) = v;
      }
    }
    __syncthreads();
    bf16x8 af[4], bfr[4];
#pragma unroll
    for (int m = 0; m < 4; ++m)
      af[m] = *reinterpret_cast<const bf16x8*>(&lA[(wr * 64 + m * 16 + lr) * 40 + lg * 8]);
#pragma unroll
    for (int n = 0; n < 4; ++n)
      bfr[n] = *reinterpret_cast<const bf16x8*>(&lB[(wc * 64 + n * 16 + lr) * 40 + lg * 8]);
#pragma unroll
    for (int m = 0; m < 4; ++m)
#pragma unroll
      for (int n = 0; n < 4; ++n)
        acc[m][n] = MFMA16(af[m], bfr[n], acc[m][n]);
    __syncthreads();
  }
#pragma unroll
  for (int m = 0; m < 4; ++m) {
#pragma unroll
    for (int ii = 0; ii < 4; ++ii) {
      int dr = d0 + wr * 64 + m * 16 + lg * 4 + ii;
      float bs = bo[dr];
      float* orow = out + ((size_t)b * 1024 + dr) * 1024 + l0 + wc * 64 + lr;
#pragma unroll
      for (int n = 0; n < 4; ++n)
        orow[n * 16] = acc[m][n][ii] + bs;
    }
  }
}

extern "C" void kernel_launch(void* const* d_in, const int* in_sizes, int n_in,
                              void* d_out, int out_size, void* d_ws, size_t ws_size,
                              hipStream_t stream) {
  const float* x  = (const float*)d_in[0];
  const int* mask = (const int*)d_in[1];
  const float* wq = (const float*)d_in[2];
  const float* bq = (const float*)d_in[3];
  const float* wk = (const float*)d_in[4];
  const float* bk = (const float*)d_in[5];
  const float* wv = (const float*)d_in[6];
  const float* bv = (const float*)d_in[7];
  const float* wo = (const float*)d_in[8];
  const float* bo = (const float*)d_in[9];
  float* out = (float*)d_out;

  const size_t MB64 = (size_t)64 << 20;
  const size_t NEED = (size_t)264 << 20;

  if (ws_size >= NEED) {
    unsigned short* xT   = (unsigned short*)d_ws;
    unsigned short* Q    = (unsigned short*)((char*)d_ws + MB64);
    unsigned short* K    = (unsigned short*)((char*)d_ws + 2 * MB64);
    unsigned short* Vt   = (unsigned short*)((char*)d_ws + 3 * MB64);
    unsigned short* Wqkv = (unsigned short*)((char*)d_ws + 4 * MB64);
    unsigned short* Wo   = Wqkv + (size_t)3 * 1048576;

    x_transpose<<<dim3(16, 16, 32), 256, 0, stream>>>(x, xT);
    w_convert<<<dim3(1024, 4), 256, 0, stream>>>(wq, wk, wv, wo, Wqkv, Wo);
    qkv_gemm8<<<dim3(1536), 512, 0, stream>>>(xT, Wqkv, bq, bk, bv, Q, K, Vt);
    flash_attn<<<dim3(2048), 256, 0, stream>>>(Q, K, Vt, mask, Q);
    out_gemm8<<<dim3(16, 32), 512, 0, stream>>>(Wo, Q, bo, out);
  } else {
    unsigned short* Q  = (unsigned short*)d_ws;
    unsigned short* K  = Q + (size_t)33554432;
    unsigned short* Vt = K + (size_t)33554432;
    qkv_proj_old<<<dim3(64, 32, 3), 256, 0, stream>>>(x, wq, wk, wv, bq, bk, bv, Q, K, Vt);
    flash_attn<<<dim3(2048), 256, 0, stream>>>(Q, K, Vt, mask, Q);
    out_proj_old<<<dim3(64, 32), 256, 0, stream>>>(Q, wo, bo, out);
  }
}